// Round 1
// baseline (336.082 us; speedup 1.0000x reference)
//
#include <hip/hip_runtime.h>

typedef unsigned short u16;
typedef unsigned int   u32;
typedef short bf16x8 __attribute__((ext_vector_type(8)));
typedef float f32x4  __attribute__((ext_vector_type(4)));

#define QK_SCALE 0.18033688011112042f   // 0.125 * log2(e): fold softmax exp2 into q

__device__ __forceinline__ u16 f2bf(float f) {
  u32 u = __builtin_bit_cast(u32, f);
  u = (u + 0x7FFFu + ((u >> 16) & 1u)) >> 16;   // RNE
  return (u16)u;
}

__device__ __forceinline__ void gload16(void* lds, const void* g) {
  __builtin_amdgcn_global_load_lds(
      (const __attribute__((address_space(1))) u32*)g,
      (__attribute__((address_space(3))) u32*)lds, 16, 0, 0);
}

__device__ __forceinline__ bf16x8 ld8(const void* p) {
  return *(const bf16x8*)p;
}

// ---------------- kernel 1: fp32 -> bf16 convert (x, in_proj_w, out_w) ----
__global__ __launch_bounds__(256) void cvt_kernel(
    const float* __restrict__ x, const float* __restrict__ w1,
    const float* __restrict__ w2,
    u16* __restrict__ xb, u16* __restrict__ wb, u16* __restrict__ ob) {
  int i = blockIdx.x * 256 + threadIdx.x;      // one float4 per thread
  const float* src; u16* dst; int off;
  if (i < 1048576)            { src = x;  dst = xb; off = i; }
  else if (i < 1048576+196608){ src = w1; dst = wb; off = i - 1048576; }
  else                        { src = w2; dst = ob; off = i - 1245184; }
  float4 v = ((const float4*)src)[off];
  ushort4 o;
  o.x = f2bf(v.x); o.y = f2bf(v.y); o.z = f2bf(v.z); o.w = f2bf(v.w);
  ((ushort4*)dst)[off] = o;
}

// ---------------- kernel 2/5: bf16 GEMM  C = A * B^T  (+bias) -------------
// A[M][K], B[N][K] bf16.  128x128 tile, BK=64, 4 waves (2x2), 64x64/wave.
// MODE 0: qkv epilogue (scatter q/k/v per-head, q pre-scaled)
// MODE 1: plain fp32 output
template<int MODE>
__global__ __launch_bounds__(256, 2) void gemm_bt(
    const u16* __restrict__ A, const u16* __restrict__ Bm,
    const float* __restrict__ bias,
    u16* __restrict__ q_out, u16* __restrict__ k_out, u16* __restrict__ v_out,
    float* __restrict__ f_out, int M, int N, int K) {
  __shared__ __attribute__((aligned(16))) u16 As[128 * 64];
  __shared__ __attribute__((aligned(16))) u16 Bs[128 * 64];
  const int tid = threadIdx.x, lane = tid & 63, w = tid >> 6;
  const int wm = w >> 1, wn = w & 1;
  const int lo = lane & 15, hi = lane >> 4;
  const int m0 = blockIdx.x * 128, n0 = blockIdx.y * 128;
  f32x4 acc[4][4] = {};
  const int srow = lane >> 3;                   // row within 8-row chunk
  const int skc  = (lane & 7) ^ srow;           // pre-swizzled source chunk
  const int nk = K >> 6;
  for (int kt = 0; kt < nk; ++kt) {
    __syncthreads();                            // WAR on LDS
    const int k0 = kt * 64;
#pragma unroll
    for (int c = 0; c < 4; ++c) {
      const int ch = w * 4 + c;                 // 0..15, wave-uniform
      const int row = ch * 8 + srow;
      gload16((char*)As + ch * 1024, A  + (size_t)(m0 + row) * K + k0 + skc * 8);
      gload16((char*)Bs + ch * 1024, Bm + (size_t)(n0 + row) * K + k0 + skc * 8);
    }
    __syncthreads();                            // vmcnt(0) drained by compiler
#pragma unroll
    for (int kk = 0; kk < 2; ++kk) {
      bf16x8 af[4], bfr[4];
#pragma unroll
      for (int mi = 0; mi < 4; ++mi) {
        const int row = wm * 64 + mi * 16 + lo;
        const int kc = kk * 4 + hi;
        af[mi] = ld8((const char*)As + row * 128 + ((kc ^ (row & 7)) << 4));
      }
#pragma unroll
      for (int ni = 0; ni < 4; ++ni) {
        const int row = wn * 64 + ni * 16 + lo;
        const int kc = kk * 4 + hi;
        bfr[ni] = ld8((const char*)Bs + row * 128 + ((kc ^ (row & 7)) << 4));
      }
#pragma unroll
      for (int mi = 0; mi < 4; ++mi)
#pragma unroll
        for (int ni = 0; ni < 4; ++ni)
          acc[mi][ni] = __builtin_amdgcn_mfma_f32_16x16x32_bf16(
              af[mi], bfr[ni], acc[mi][ni], 0, 0, 0);
    }
  }
  // epilogue
#pragma unroll
  for (int mi = 0; mi < 4; ++mi)
#pragma unroll
    for (int ni = 0; ni < 4; ++ni) {
      const int gn = n0 + wn * 64 + ni * 16 + lo;
      const float bv = bias[gn];
#pragma unroll
      for (int r = 0; r < 4; ++r) {
        const int gm = m0 + wm * 64 + mi * 16 + hi * 4 + r;
        float val = acc[mi][ni][r] + bv;
        if (MODE == 0) {
          const int s = gm >> 1, b = gm & 1;
          const int sec = gn >> 9, e = gn & 511;
          const int h = e >> 6, d = e & 63;
          const size_t o = (((size_t)(b * 8 + h) * 4096 + s) << 6) + d;
          if (sec == 0)      q_out[o] = f2bf(val * QK_SCALE);
          else if (sec == 1) k_out[o] = f2bf(val);
          else               v_out[o] = f2bf(val);
        } else {
          f_out[(size_t)gm * N + gn] = val;
        }
      }
    }
}

// ---------------- kernel 3: V [BH][S][64] -> V^T [BH][64][S] --------------
__global__ __launch_bounds__(256) void transpose_v(
    const u16* __restrict__ v, u16* __restrict__ vt) {
  __shared__ __attribute__((aligned(16))) u16 T[64 * 72];
  const int bh = blockIdx.y, s0 = blockIdx.x * 64;
  const int t = threadIdx.x;
#pragma unroll
  for (int i = 0; i < 2; ++i) {
    const int idx = t + i * 256;                // 0..511
    const int row = idx >> 3, c = idx & 7;
    uint4 d = *(const uint4*)(v + ((size_t)bh * 4096 + s0 + row) * 64 + c * 8);
    *(uint4*)(&T[row * 72 + c * 8]) = d;
  }
  __syncthreads();
#pragma unroll
  for (int i = 0; i < 2; ++i) {
    const int idx = t + i * 256;
    const int dcol = idx >> 3, sc = idx & 7;
    u16 tmp[8];
#pragma unroll
    for (int j = 0; j < 8; ++j) tmp[j] = T[(sc * 8 + j) * 72 + dcol];
    *(uint4*)(vt + ((size_t)bh * 64 + dcol) * 4096 + s0 + sc * 8) = *(const uint4*)tmp;
  }
}

// ---------------- kernel 4: flash attention -------------------------------
// 4 independent waves/block, 32 q-rows/wave, KV blocks of 64, 16x16x32 MFMA.
// q pre-scaled by 0.125*log2(e) -> softmax in exp2 domain.
__global__ __launch_bounds__(256, 2) void fa_kernel(
    const u16* __restrict__ q, const u16* __restrict__ k,
    const u16* __restrict__ vt, u16* __restrict__ attn) {
  __shared__ __attribute__((aligned(16))) u16 P_lds[4 * 32 * 64];
  const int tid = threadIdx.x, lane = tid & 63, w = tid >> 6;
  const int lo = lane & 15, hi = lane >> 4;
  // XCD-aware mapping: 2 heads per XCD so K/V (2 MB) fit that XCD's L2
  const int wg = blockIdx.x;                    // 0..511
  const int xcd = wg & 7, idx = wg >> 3;
  const int bh = xcd * 2 + (idx >> 5), qb = idx & 31;
  const int q0 = qb * 128 + w * 32;
  const size_t hb = (size_t)bh * 4096 * 64;
  bf16x8 qf[2][2];
#pragma unroll
  for (int mi = 0; mi < 2; ++mi)
#pragma unroll
    for (int kf = 0; kf < 2; ++kf)
      qf[mi][kf] = ld8(q + hb + (size_t)(q0 + mi * 16 + lo) * 64 + kf * 32 + hi * 8);
  f32x4 acc[2][4] = {};
  float mrun[2][4], lrun[2][4];
#pragma unroll
  for (int mi = 0; mi < 2; ++mi)
#pragma unroll
    for (int r = 0; r < 4; ++r) { mrun[mi][r] = -1e30f; lrun[mi][r] = 0.f; }
  char* pl = (char*)P_lds + w * 4096;
  const u16* vbase = vt + (size_t)bh * 64 * 4096;

  for (int kb = 0; kb < 64; ++kb) {
    const int kv0 = kb * 64;
    f32x4 sa[2][4] = {};
#pragma unroll
    for (int nt = 0; nt < 4; ++nt) {
      const u16* kp = k + hb + (size_t)(kv0 + nt * 16 + lo) * 64 + hi * 8;
      bf16x8 k0 = ld8(kp);
      bf16x8 k1 = ld8(kp + 32);
      sa[0][nt] = __builtin_amdgcn_mfma_f32_16x16x32_bf16(qf[0][0], k0, sa[0][nt], 0,0,0);
      sa[0][nt] = __builtin_amdgcn_mfma_f32_16x16x32_bf16(qf[0][1], k1, sa[0][nt], 0,0,0);
      sa[1][nt] = __builtin_amdgcn_mfma_f32_16x16x32_bf16(qf[1][0], k0, sa[1][nt], 0,0,0);
      sa[1][nt] = __builtin_amdgcn_mfma_f32_16x16x32_bf16(qf[1][1], k1, sa[1][nt], 0,0,0);
    }
    // online softmax (wave-parallel; rows = hi*4+r, cols spread over 16 lanes x 4 nt)
    float fsc[2][4];
#pragma unroll
    for (int mi = 0; mi < 2; ++mi)
#pragma unroll
      for (int r = 0; r < 4; ++r) {
        float pm = fmaxf(fmaxf(sa[mi][0][r], sa[mi][1][r]),
                         fmaxf(sa[mi][2][r], sa[mi][3][r]));
        pm = fmaxf(pm, __shfl_xor(pm, 1));
        pm = fmaxf(pm, __shfl_xor(pm, 2));
        pm = fmaxf(pm, __shfl_xor(pm, 4));
        pm = fmaxf(pm, __shfl_xor(pm, 8));
        const float mn = fmaxf(mrun[mi][r], pm);
        const float f = __builtin_amdgcn_exp2f(mrun[mi][r] - mn);
        mrun[mi][r] = mn;
        fsc[mi][r] = f;
        lrun[mi][r] *= f;
      }
#pragma unroll
    for (int mi = 0; mi < 2; ++mi)
#pragma unroll
      for (int nt = 0; nt < 4; ++nt)
#pragma unroll
        for (int r = 0; r < 4; ++r) {
          const float p = __builtin_amdgcn_exp2f(sa[mi][nt][r] - mrun[mi][r]);
          lrun[mi][r] += p;                      // per-lane partial; reduce at end
          const int row = mi * 16 + hi * 4 + r;
          const int byte = row * 128 + (nt * 16 + lo) * 2;
          *(u16*)(pl + (byte ^ ((row & 7) << 4))) = f2bf(p);
        }
#pragma unroll
    for (int mi = 0; mi < 2; ++mi)
#pragma unroll
      for (int dt = 0; dt < 4; ++dt)
#pragma unroll
        for (int r = 0; r < 4; ++r) acc[mi][dt][r] *= fsc[mi][r];
    asm volatile("s_waitcnt lgkmcnt(0)" ::: "memory");
    bf16x8 pa[2][2];
#pragma unroll
    for (int mi = 0; mi < 2; ++mi)
#pragma unroll
      for (int kf = 0; kf < 2; ++kf) {
        const int row = mi * 16 + lo;
        const int byte = row * 128 + kf * 64 + hi * 16;
        pa[mi][kf] = ld8(pl + (byte ^ ((row & 7) << 4)));
      }
#pragma unroll
    for (int dt = 0; dt < 4; ++dt) {
      const u16* vp = vbase + (size_t)(dt * 16 + lo) * 4096 + kv0 + hi * 8;
      bf16x8 v0 = ld8(vp);
      bf16x8 v1 = ld8(vp + 32);
      acc[0][dt] = __builtin_amdgcn_mfma_f32_16x16x32_bf16(pa[0][0], v0, acc[0][dt], 0,0,0);
      acc[0][dt] = __builtin_amdgcn_mfma_f32_16x16x32_bf16(pa[0][1], v1, acc[0][dt], 0,0,0);
      acc[1][dt] = __builtin_amdgcn_mfma_f32_16x16x32_bf16(pa[1][0], v0, acc[1][dt], 0,0,0);
      acc[1][dt] = __builtin_amdgcn_mfma_f32_16x16x32_bf16(pa[1][1], v1, acc[1][dt], 0,0,0);
    }
  }
  // finalize: reduce l across 16 lanes, normalize, write [S,B,E] bf16
  const int b = bh >> 3, h = bh & 7;
#pragma unroll
  for (int mi = 0; mi < 2; ++mi) {
    float inv[4];
#pragma unroll
    for (int r = 0; r < 4; ++r) {
      float l = lrun[mi][r];
      l += __shfl_xor(l, 1); l += __shfl_xor(l, 2);
      l += __shfl_xor(l, 4); l += __shfl_xor(l, 8);
      inv[r] = 1.0f / l;
    }
#pragma unroll
    for (int dt = 0; dt < 4; ++dt)
#pragma unroll
      for (int r = 0; r < 4; ++r) {
        const int s = q0 + mi * 16 + hi * 4 + r;
        const int col = h * 64 + dt * 16 + lo;
        attn[(size_t)(s * 2 + b) * 512 + col] = f2bf(acc[mi][dt][r] * inv[r]);
      }
  }
}

// ---------------- launcher ------------------------------------------------
extern "C" void kernel_launch(void* const* d_in, const int* in_sizes, int n_in,
                              void* d_out, int out_size, void* d_ws, size_t ws_size,
                              hipStream_t stream) {
  const float* x     = (const float*)d_in[0];
  const float* w_in  = (const float*)d_in[1];
  const float* b_in  = (const float*)d_in[2];
  const float* w_out = (const float*)d_in[3];
  const float* b_out = (const float*)d_in[4];
  float* out = (float*)d_out;
  char* ws = (char*)d_ws;
  // layout (bytes):
  u16* xb  = (u16*)(ws);               // 8,388,608   x bf16 [8192][512]
  u16* wb  = (u16*)(ws + 8388608);     // 1,572,864   in_proj_w bf16 [1536][512]
  u16* ob  = (u16*)(ws + 9961472);     //   524,288   out_w bf16 [512][512]
  u16* qb  = (u16*)(ws + 10485760);    // 8,388,608   q bf16 [16][4096][64] (pre-scaled)
  u16* kb  = (u16*)(ws + 18874368);    // 8,388,608   k
  u16* vb  = (u16*)(ws + 27262976);    // 8,388,608   v
  u16* vtb = (u16*)(ws + 35651584);    // 8,388,608   v^T [16][64][4096]
  u16* attn = xb;                      // alias: xb fully consumed by gemm<0>

  cvt_kernel<<<5120, 256, 0, stream>>>(x, w_in, w_out, xb, wb, ob);
  gemm_bt<0><<<dim3(64, 12), 256, 0, stream>>>(xb, wb, b_in, qb, kb, vb,
                                               nullptr, 8192, 1536, 512);
  transpose_v<<<dim3(64, 16), 256, 0, stream>>>(vb, vtb);
  fa_kernel<<<512, 256, 0, stream>>>(qb, kb, vtb, attn);
  gemm_bt<1><<<dim3(64, 4), 256, 0, stream>>>(attn, ob, b_out, nullptr, nullptr,
                                              nullptr, out, 8192, 512, 512);
}

// Round 2
// 307.778 us; speedup vs baseline: 1.0920x; 1.0920x over previous
//
#include <hip/hip_runtime.h>

typedef unsigned short u16;
typedef unsigned int   u32;
typedef short bf16x8 __attribute__((ext_vector_type(8)));
typedef float f32x4  __attribute__((ext_vector_type(4)));

#define QK_SCALE 0.18033688011112042f   // 0.125 * log2(e): fold softmax exp2 into q

__device__ __forceinline__ u16 f2bf(float f) {
  u32 u = __builtin_bit_cast(u32, f);
  u = (u + 0x7FFFu + ((u >> 16) & 1u)) >> 16;   // RNE
  return (u16)u;
}

__device__ __forceinline__ void gload16(void* lds, const void* g) {
  __builtin_amdgcn_global_load_lds(
      (const __attribute__((address_space(1))) u32*)g,
      (__attribute__((address_space(3))) u32*)lds, 16, 0, 0);
}

__device__ __forceinline__ bf16x8 ld8(const void* p) {
  return *(const bf16x8*)p;
}

// ---------------- kernel 1: fp32 -> bf16 convert (x, in_proj_w, out_w) ----
__global__ __launch_bounds__(256) void cvt_kernel(
    const float* __restrict__ x, const float* __restrict__ w1,
    const float* __restrict__ w2,
    u16* __restrict__ xb, u16* __restrict__ wb, u16* __restrict__ ob) {
  int i = blockIdx.x * 256 + threadIdx.x;      // one float4 per thread
  const float* src; u16* dst; int off;
  if (i < 1048576)            { src = x;  dst = xb; off = i; }
  else if (i < 1048576+196608){ src = w1; dst = wb; off = i - 1048576; }
  else                        { src = w2; dst = ob; off = i - 1245184; }
  float4 v = ((const float4*)src)[off];
  ushort4 o;
  o.x = f2bf(v.x); o.y = f2bf(v.y); o.z = f2bf(v.z); o.w = f2bf(v.w);
  ((ushort4*)dst)[off] = o;
}

// ---------------- kernel 2/5: bf16 GEMM  C = A * B^T  (+bias) -------------
// A[M][K], B[N][K] bf16.  128x128 tile, BK=64, 4 waves (2x2), 64x64/wave.
// MODE 0: qkv epilogue (scatter q/k/v per-head, q pre-scaled)
// MODE 1: plain fp32 output
template<int MODE>
__global__ __launch_bounds__(256, 2) void gemm_bt(
    const u16* __restrict__ A, const u16* __restrict__ Bm,
    const float* __restrict__ bias,
    u16* __restrict__ q_out, u16* __restrict__ k_out, u16* __restrict__ v_out,
    float* __restrict__ f_out, int M, int N, int K) {
  __shared__ __attribute__((aligned(16))) u16 As[128 * 64];
  __shared__ __attribute__((aligned(16))) u16 Bs[128 * 64];
  const int tid = threadIdx.x, lane = tid & 63, w = tid >> 6;
  const int wm = w >> 1, wn = w & 1;
  const int lo = lane & 15, hi = lane >> 4;
  const int m0 = blockIdx.x * 128, n0 = blockIdx.y * 128;
  f32x4 acc[4][4] = {};
  const int srow = lane >> 3;                   // row within 8-row chunk
  const int skc  = (lane & 7) ^ srow;           // pre-swizzled source chunk
  const int nk = K >> 6;
  for (int kt = 0; kt < nk; ++kt) {
    __syncthreads();                            // WAR on LDS
    const int k0 = kt * 64;
#pragma unroll
    for (int c = 0; c < 4; ++c) {
      const int ch = w * 4 + c;                 // 0..15, wave-uniform
      const int row = ch * 8 + srow;
      gload16((char*)As + ch * 1024, A  + (size_t)(m0 + row) * K + k0 + skc * 8);
      gload16((char*)Bs + ch * 1024, Bm + (size_t)(n0 + row) * K + k0 + skc * 8);
    }
    __syncthreads();                            // vmcnt(0) drained by compiler
#pragma unroll
    for (int kk = 0; kk < 2; ++kk) {
      bf16x8 af[4], bfr[4];
#pragma unroll
      for (int mi = 0; mi < 4; ++mi) {
        const int row = wm * 64 + mi * 16 + lo;
        const int kc = kk * 4 + hi;
        af[mi] = ld8((const char*)As + row * 128 + ((kc ^ (row & 7)) << 4));
      }
#pragma unroll
      for (int ni = 0; ni < 4; ++ni) {
        const int row = wn * 64 + ni * 16 + lo;
        const int kc = kk * 4 + hi;
        bfr[ni] = ld8((const char*)Bs + row * 128 + ((kc ^ (row & 7)) << 4));
      }
#pragma unroll
      for (int mi = 0; mi < 4; ++mi)
#pragma unroll
        for (int ni = 0; ni < 4; ++ni)
          acc[mi][ni] = __builtin_amdgcn_mfma_f32_16x16x32_bf16(
              af[mi], bfr[ni], acc[mi][ni], 0, 0, 0);
    }
  }
  // epilogue
#pragma unroll
  for (int mi = 0; mi < 4; ++mi)
#pragma unroll
    for (int ni = 0; ni < 4; ++ni) {
      const int gn = n0 + wn * 64 + ni * 16 + lo;
      const float bv = bias[gn];
#pragma unroll
      for (int r = 0; r < 4; ++r) {
        const int gm = m0 + wm * 64 + mi * 16 + hi * 4 + r;
        float val = acc[mi][ni][r] + bv;
        if (MODE == 0) {
          const int s = gm >> 1, b = gm & 1;
          const int sec = gn >> 9, e = gn & 511;
          const int h = e >> 6, d = e & 63;
          const size_t o = (((size_t)(b * 8 + h) * 4096 + s) << 6) + d;
          if (sec == 0)      q_out[o] = f2bf(val * QK_SCALE);
          else if (sec == 1) k_out[o] = f2bf(val);
          else               v_out[o] = f2bf(val);
        } else {
          f_out[(size_t)gm * N + gn] = val;
        }
      }
    }
}

// ---------------- kernel 3: V [BH][S][64] -> V^T [BH][64][S] --------------
__global__ __launch_bounds__(256) void transpose_v(
    const u16* __restrict__ v, u16* __restrict__ vt) {
  __shared__ __attribute__((aligned(16))) u16 T[64 * 72];
  const int bh = blockIdx.y, s0 = blockIdx.x * 64;
  const int t = threadIdx.x;
#pragma unroll
  for (int i = 0; i < 2; ++i) {
    const int idx = t + i * 256;                // 0..511
    const int row = idx >> 3, c = idx & 7;
    uint4 d = *(const uint4*)(v + ((size_t)bh * 4096 + s0 + row) * 64 + c * 8);
    *(uint4*)(&T[row * 72 + c * 8]) = d;
  }
  __syncthreads();
#pragma unroll
  for (int i = 0; i < 2; ++i) {
    const int idx = t + i * 256;
    const int dcol = idx >> 3, sc = idx & 7;
    u16 tmp[8];
#pragma unroll
    for (int j = 0; j < 8; ++j) tmp[j] = T[(sc * 8 + j) * 72 + dcol];
    *(uint4*)(vt + ((size_t)bh * 64 + dcol) * 4096 + s0 + sc * 8) = *(const uint4*)tmp;
  }
}

// ---------------- kernel 4: flash attention -------------------------------
// 4 waves/block, 16 q-rows/wave (block = 64 rows) -> grid 1024, 4 blk/CU.
// K tile staged in LDS per block (shared by 4 waves, XOR-swizzled);
// V^T read from L2 into regs (prefetched under softmax); defer-max (THR=8).
// q pre-scaled by 0.125*log2(e) -> softmax in exp2 domain.
__global__ __launch_bounds__(256, 4) void fa_kernel(
    const u16* __restrict__ q, const u16* __restrict__ k,
    const u16* __restrict__ vt, u16* __restrict__ attn) {
  __shared__ __attribute__((aligned(16))) u16 K_lds[64 * 64];   // 8 KB
  __shared__ __attribute__((aligned(16))) u16 P_lds[4 * 16 * 64]; // 8 KB
  const int tid = threadIdx.x, lane = tid & 63, w = tid >> 6;
  const int lo = lane & 15, hi = lane >> 4;
  // XCD-aware mapping: 2 heads per XCD so K/V (2 MB) fit that XCD's L2
  const int wg = blockIdx.x;                    // 0..1023
  const int xcd = wg & 7, idx = wg >> 3;        // idx 0..127
  const int bh = xcd * 2 + (idx >> 6), qb = idx & 63;
  const int q0 = qb * 64 + w * 16;
  const size_t hb = (size_t)bh * 4096 * 64;
  bf16x8 qf[2];
#pragma unroll
  for (int kf = 0; kf < 2; ++kf)
    qf[kf] = ld8(q + hb + (size_t)(q0 + lo) * 64 + kf * 32 + hi * 8);
  f32x4 acc[4] = {};
  float mrun[4], lrun[4];
#pragma unroll
  for (int r = 0; r < 4; ++r) { mrun[r] = -1e30f; lrun[r] = 0.f; }
  char* pl = (char*)P_lds + w * 2048;
  const u16* vbase = vt + (size_t)bh * 64 * 4096;
  const int srow = lane >> 3;                   // row within 8-row chunk
  const int skc  = (lane & 7) ^ srow;           // pre-swizzled source chunk

  for (int kb = 0; kb < 64; ++kb) {
    const int kv0 = kb * 64;
    __syncthreads();                            // WAR: everyone done with K_lds
#pragma unroll
    for (int rnd = 0; rnd < 2; ++rnd) {
      const int ch = rnd * 4 + w;               // 0..7, wave-uniform
      gload16((char*)K_lds + ch * 1024,
              k + hb + (size_t)(kv0 + ch * 8 + srow) * 64 + skc * 8);
    }
    __syncthreads();                            // K tile ready (vmcnt drained)
    // QK^T: S[16 q][64 kv]
    f32x4 sa[4] = {};
    __builtin_amdgcn_s_setprio(1);
#pragma unroll
    for (int nt = 0; nt < 4; ++nt) {
      const int row = nt * 16 + lo;
#pragma unroll
      for (int kf = 0; kf < 2; ++kf) {
        bf16x8 kfr = ld8((const char*)K_lds + row * 128 +
                         (((kf * 4 + hi) ^ (row & 7)) << 4));
        sa[nt] = __builtin_amdgcn_mfma_f32_16x16x32_bf16(qf[kf], kfr, sa[nt], 0,0,0);
      }
    }
    __builtin_amdgcn_s_setprio(0);
    // V prefetch (latency hides under softmax)
    bf16x8 vf[4][2];
#pragma unroll
    for (int dt = 0; dt < 4; ++dt) {
      const u16* vp = vbase + (size_t)(dt * 16 + lo) * 4096 + kv0 + hi * 8;
      vf[dt][0] = ld8(vp);
      vf[dt][1] = ld8(vp + 32);
    }
    // defer-max online softmax (rows = hi*4+r, cols over 16 lanes x 4 nt)
    float pm[4];
#pragma unroll
    for (int r = 0; r < 4; ++r)
      pm[r] = fmaxf(fmaxf(sa[0][r], sa[1][r]), fmaxf(sa[2][r], sa[3][r]));
    const int ok = (pm[0] - mrun[0] <= 8.f) & (pm[1] - mrun[1] <= 8.f) &
                   (pm[2] - mrun[2] <= 8.f) & (pm[3] - mrun[3] <= 8.f);
    if (!__all(ok)) {
#pragma unroll
      for (int r = 0; r < 4; ++r) {
        float p = pm[r];
        p = fmaxf(p, __shfl_xor(p, 1));
        p = fmaxf(p, __shfl_xor(p, 2));
        p = fmaxf(p, __shfl_xor(p, 4));
        p = fmaxf(p, __shfl_xor(p, 8));
        const float mn = fmaxf(mrun[r], p);
        const float f = __builtin_amdgcn_exp2f(mrun[r] - mn);
        mrun[r] = mn;
        lrun[r] *= f;
#pragma unroll
        for (int dt = 0; dt < 4; ++dt) acc[dt][r] *= f;
      }
    }
    // P = exp2(S - m), accumulate l, write P to LDS (swizzled)
#pragma unroll
    for (int nt = 0; nt < 4; ++nt)
#pragma unroll
      for (int r = 0; r < 4; ++r) {
        const float p = __builtin_amdgcn_exp2f(sa[nt][r] - mrun[r]);
        lrun[r] += p;                           // per-lane partial; reduce at end
        const int row = hi * 4 + r;
        const int byte = (row * 128 + (nt * 16 + lo) * 2) ^ ((row & 7) << 4);
        *(u16*)(pl + byte) = f2bf(p);
      }
    asm volatile("s_waitcnt lgkmcnt(0)" ::: "memory");
    __builtin_amdgcn_sched_barrier(0);
    bf16x8 pa[2];
#pragma unroll
    for (int kf = 0; kf < 2; ++kf) {
      const int byte = (lo * 128 + kf * 64 + hi * 16) ^ ((lo & 7) << 4);
      pa[kf] = ld8(pl + byte);
    }
    __builtin_amdgcn_s_setprio(1);
#pragma unroll
    for (int dt = 0; dt < 4; ++dt) {
      acc[dt] = __builtin_amdgcn_mfma_f32_16x16x32_bf16(pa[0], vf[dt][0], acc[dt], 0,0,0);
      acc[dt] = __builtin_amdgcn_mfma_f32_16x16x32_bf16(pa[1], vf[dt][1], acc[dt], 0,0,0);
    }
    __builtin_amdgcn_s_setprio(0);
  }
  // finalize: reduce l across 16 lanes, normalize, write [S,B,E] bf16
  const int b = bh >> 3, h = bh & 7;
  float inv[4];
#pragma unroll
  for (int r = 0; r < 4; ++r) {
    float l = lrun[r];
    l += __shfl_xor(l, 1); l += __shfl_xor(l, 2);
    l += __shfl_xor(l, 4); l += __shfl_xor(l, 8);
    inv[r] = 1.0f / l;
  }
#pragma unroll
  for (int dt = 0; dt < 4; ++dt)
#pragma unroll
    for (int r = 0; r < 4; ++r) {
      const int s = q0 + hi * 4 + r;
      const int col = h * 64 + dt * 16 + lo;
      attn[(size_t)(s * 2 + b) * 512 + col] = f2bf(acc[dt][r] * inv[r]);
    }
}

// ---------------- launcher ------------------------------------------------
extern "C" void kernel_launch(void* const* d_in, const int* in_sizes, int n_in,
                              void* d_out, int out_size, void* d_ws, size_t ws_size,
                              hipStream_t stream) {
  const float* x     = (const float*)d_in[0];
  const float* w_in  = (const float*)d_in[1];
  const float* b_in  = (const float*)d_in[2];
  const float* w_out = (const float*)d_in[3];
  const float* b_out = (const float*)d_in[4];
  float* out = (float*)d_out;
  char* ws = (char*)d_ws;
  // layout (bytes):
  u16* xb  = (u16*)(ws);               // 8,388,608   x bf16 [8192][512]
  u16* wb  = (u16*)(ws + 8388608);     // 1,572,864   in_proj_w bf16 [1536][512]
  u16* ob  = (u16*)(ws + 9961472);     //   524,288   out_w bf16 [512][512]
  u16* qb  = (u16*)(ws + 10485760);    // 8,388,608   q bf16 [16][4096][64] (pre-scaled)
  u16* kb  = (u16*)(ws + 18874368);    // 8,388,608   k
  u16* vb  = (u16*)(ws + 27262976);    // 8,388,608   v
  u16* vtb = (u16*)(ws + 35651584);    // 8,388,608   v^T [16][64][4096]
  u16* attn = xb;                      // alias: xb fully consumed by gemm<0>

  cvt_kernel<<<5120, 256, 0, stream>>>(x, w_in, w_out, xb, wb, ob);
  gemm_bt<0><<<dim3(64, 12), 256, 0, stream>>>(xb, wb, b_in, qb, kb, vb,
                                               nullptr, 8192, 1536, 512);
  transpose_v<<<dim3(64, 16), 256, 0, stream>>>(vb, vtb);
  fa_kernel<<<1024, 256, 0, stream>>>(qb, kb, vtb, attn);
  gemm_bt<1><<<dim3(64, 4), 256, 0, stream>>>(attn, ob, b_out, nullptr, nullptr,
                                              nullptr, out, 8192, 512, 512);
}

// Round 3
// 172.967 us; speedup vs baseline: 1.9430x; 1.7794x over previous
//
#include <hip/hip_runtime.h>

typedef unsigned short u16;
typedef unsigned int   u32;
typedef short bf16x8 __attribute__((ext_vector_type(8)));
typedef float f32x4  __attribute__((ext_vector_type(4)));
typedef float f32x16 __attribute__((ext_vector_type(16)));
typedef u32   u32x4  __attribute__((ext_vector_type(4)));

#define QK_SCALE 0.18033688011112042f   // 0.125 * log2(e): fold softmax exp2 into q

__device__ __forceinline__ u16 f2bf(float f) {
  u32 u = __builtin_bit_cast(u32, f);
  u = (u + 0x7FFFu + ((u >> 16) & 1u)) >> 16;   // RNE
  return (u16)u;
}

__device__ __forceinline__ u32 cvtpk(float lo, float hi) {
  u32 r;
  asm("v_cvt_pk_bf16_f32 %0, %1, %2" : "=v"(r) : "v"(lo), "v"(hi));
  return r;
}

__device__ __forceinline__ void gload16(void* lds, const void* g) {
  __builtin_amdgcn_global_load_lds(
      (const __attribute__((address_space(1))) u32*)g,
      (__attribute__((address_space(3))) u32*)lds, 16, 0, 0);
}

__device__ __forceinline__ bf16x8 ld8(const void* p) {
  return *(const bf16x8*)p;
}

// ---------------- kernel 1: fp32 -> bf16 convert (x, in_proj_w, out_w) ----
__global__ __launch_bounds__(256) void cvt_kernel(
    const float* __restrict__ x, const float* __restrict__ w1,
    const float* __restrict__ w2,
    u16* __restrict__ xb, u16* __restrict__ wb, u16* __restrict__ ob) {
  int i = blockIdx.x * 256 + threadIdx.x;      // one float4 per thread
  const float* src; u16* dst; int off;
  if (i < 1048576)            { src = x;  dst = xb; off = i; }
  else if (i < 1048576+196608){ src = w1; dst = wb; off = i - 1048576; }
  else                        { src = w2; dst = ob; off = i - 1245184; }
  float4 v = ((const float4*)src)[off];
  ushort4 o;
  o.x = f2bf(v.x); o.y = f2bf(v.y); o.z = f2bf(v.z); o.w = f2bf(v.w);
  ((ushort4*)dst)[off] = o;
}

// ---------------- kernel 2/5: bf16 GEMM  C = A * B^T  (+bias) -------------
template<int MODE>
__global__ __launch_bounds__(256, 2) void gemm_bt(
    const u16* __restrict__ A, const u16* __restrict__ Bm,
    const float* __restrict__ bias,
    u16* __restrict__ q_out, u16* __restrict__ k_out, u16* __restrict__ v_out,
    float* __restrict__ f_out, int M, int N, int K) {
  __shared__ __attribute__((aligned(16))) u16 As[128 * 64];
  __shared__ __attribute__((aligned(16))) u16 Bs[128 * 64];
  const int tid = threadIdx.x, lane = tid & 63, w = tid >> 6;
  const int wm = w >> 1, wn = w & 1;
  const int lo = lane & 15, hi = lane >> 4;
  const int m0 = blockIdx.x * 128, n0 = blockIdx.y * 128;
  f32x4 acc[4][4] = {};
  const int srow = lane >> 3;                   // row within 8-row chunk
  const int skc  = (lane & 7) ^ srow;           // pre-swizzled source chunk
  const int nk = K >> 6;
  for (int kt = 0; kt < nk; ++kt) {
    __syncthreads();                            // WAR on LDS
    const int k0 = kt * 64;
#pragma unroll
    for (int c = 0; c < 4; ++c) {
      const int ch = w * 4 + c;                 // 0..15, wave-uniform
      const int row = ch * 8 + srow;
      gload16((char*)As + ch * 1024, A  + (size_t)(m0 + row) * K + k0 + skc * 8);
      gload16((char*)Bs + ch * 1024, Bm + (size_t)(n0 + row) * K + k0 + skc * 8);
    }
    __syncthreads();                            // vmcnt(0) drained by compiler
#pragma unroll
    for (int kk = 0; kk < 2; ++kk) {
      bf16x8 af[4], bfr[4];
#pragma unroll
      for (int mi = 0; mi < 4; ++mi) {
        const int row = wm * 64 + mi * 16 + lo;
        const int kc = kk * 4 + hi;
        af[mi] = ld8((const char*)As + row * 128 + ((kc ^ (row & 7)) << 4));
      }
#pragma unroll
      for (int ni = 0; ni < 4; ++ni) {
        const int row = wn * 64 + ni * 16 + lo;
        const int kc = kk * 4 + hi;
        bfr[ni] = ld8((const char*)Bs + row * 128 + ((kc ^ (row & 7)) << 4));
      }
#pragma unroll
      for (int mi = 0; mi < 4; ++mi)
#pragma unroll
        for (int ni = 0; ni < 4; ++ni)
          acc[mi][ni] = __builtin_amdgcn_mfma_f32_16x16x32_bf16(
              af[mi], bfr[ni], acc[mi][ni], 0, 0, 0);
    }
  }
  // epilogue
#pragma unroll
  for (int mi = 0; mi < 4; ++mi)
#pragma unroll
    for (int ni = 0; ni < 4; ++ni) {
      const int gn = n0 + wn * 64 + ni * 16 + lo;
      const float bv = bias[gn];
#pragma unroll
      for (int r = 0; r < 4; ++r) {
        const int gm = m0 + wm * 64 + mi * 16 + hi * 4 + r;
        float val = acc[mi][ni][r] + bv;
        if (MODE == 0) {
          const int s = gm >> 1, b = gm & 1;
          const int sec = gn >> 9, e = gn & 511;
          const int h = e >> 6, d = e & 63;
          const size_t o = (((size_t)(b * 8 + h) * 4096 + s) << 6) + d;
          if (sec == 0)      q_out[o] = f2bf(val * QK_SCALE);
          else if (sec == 1) k_out[o] = f2bf(val);
          else               v_out[o] = f2bf(val);
        } else {
          f_out[(size_t)gm * N + gn] = val;
        }
      }
    }
}

// ---------------- kernel 3: V [BH][S][64] -> V^T [BH][64][S] --------------
__global__ __launch_bounds__(256) void transpose_v(
    const u16* __restrict__ v, u16* __restrict__ vt) {
  __shared__ __attribute__((aligned(16))) u16 T[64 * 72];
  const int bh = blockIdx.y, s0 = blockIdx.x * 64;
  const int t = threadIdx.x;
#pragma unroll
  for (int i = 0; i < 2; ++i) {
    const int idx = t + i * 256;                // 0..511
    const int row = idx >> 3, c = idx & 7;
    uint4 d = *(const uint4*)(v + ((size_t)bh * 4096 + s0 + row) * 64 + c * 8);
    *(uint4*)(&T[row * 72 + c * 8]) = d;
  }
  __syncthreads();
#pragma unroll
  for (int i = 0; i < 2; ++i) {
    const int idx = t + i * 256;
    const int dcol = idx >> 3, sc = idx & 7;
    u16 tmp[8];
#pragma unroll
    for (int j = 0; j < 8; ++j) tmp[j] = T[(sc * 8 + j) * 72 + dcol];
    *(uint4*)(vt + ((size_t)bh * 64 + dcol) * 4096 + s0 + sc * 8) = *(const uint4*)tmp;
  }
}

// ---------------- kernel 4: flash attention (swapped-QK, in-reg softmax) --
// 2 waves/block, 32 q-rows/wave (block = 64 rows) -> grid 1024.
// mfma_32x32x16, S^T = mfma(K, Q): lane owns P-row segment for q = lane&31.
// K and V^T double-buffered in LDS (XOR-swizzled, staged via global_load_lds
// with pre-swizzled source). One barrier per KV-64 iteration (2-phase).
// P -> bf16 A-frags via v_cvt_pk_bf16_f32 + v_permlane32_swap_b32 (T12).
// Defer-max THR=8 (T13). q pre-scaled by 0.125*log2(e) -> exp2 domain.
__global__ __launch_bounds__(128, 3) void fa_kernel(
    const u16* __restrict__ q, const u16* __restrict__ k,
    const u16* __restrict__ vt, u16* __restrict__ attn) {
  // [2 bufs][ K tile 64x64 bf16 (8KB) | V^T tile 64x64 bf16 (8KB) ]
  __shared__ __attribute__((aligned(16))) char S_lds[2][16384];
  const int tid = threadIdx.x, lane = tid & 63, w = tid >> 6;   // w = 0,1
  const int lo = lane & 31, hi5 = lane >> 5;
  // XCD-aware mapping: 2 heads per XCD so K/V (2 MB) fit that XCD's L2
  const int wg = blockIdx.x;                    // 0..1023
  const int xcd = wg & 7, idx = wg >> 3;        // idx 0..127
  const int bh = xcd * 2 + (idx >> 6), qb = idx & 63;
  const int q0 = qb * 64 + w * 32;
  const size_t hb = (size_t)bh * 4096 * 64;
  const u16* kbase = k + hb;
  const u16* vbase = vt + hb;                   // [64 d][4096 s] per head
  // Q as B-operand frags: lane holds Q[q0+lo][ds*16 + hi5*8 + j]
  bf16x8 qf[4];
#pragma unroll
  for (int ds = 0; ds < 4; ++ds)
    qf[ds] = ld8(q + hb + (size_t)(q0 + lo) * 64 + ds * 16 + hi5 * 8);

  f32x16 acc[2] = {};                 // O[q=crow(r,hi5)][dv=ds2*32+lo]
  float mrun = -1e30f, lrun = 0.f;    // softmax state for q = lo (dup per half)

  const int srow8 = lane >> 3;        // row within 8-row chunk
  const int skc   = (lane & 7) ^ srow8;  // pre-swizzled source 16B-slot

  // stage K[kv0..+64][64] and V^T[0..64 d][kv0..+64] into buf (linear LDS,
  // source pre-swizzled so reads use byte ^ ((row&7)<<4))
#define STAGE(buf, kv0)                                                       \
  {                                                                           \
    char* sb = S_lds[buf];                                                    \
    _Pragma("unroll")                                                         \
    for (int i = 0; i < 4; ++i) {                                             \
      const int c = w + i * 2;            /* chunks 0..7, wave-uniform */     \
      const int row = c * 8 + srow8;                                          \
      gload16(sb + c * 1024,                                                  \
              kbase + (size_t)((kv0) + row) * 64 + skc * 8);                  \
      gload16(sb + 8192 + c * 1024,                                           \
              vbase + (size_t)row * 4096 + (kv0) + skc * 8);                  \
    }                                                                         \
  }

  STAGE(0, 0);
  __syncthreads();

  for (int kb = 0; kb < 64; ++kb) {
    const int cur = kb & 1;
    if (kb < 63) STAGE(cur ^ 1, (kb + 1) * 64);
    const char* kl = S_lds[cur];
    const char* vl = S_lds[cur] + 8192;
#pragma unroll
    for (int kvs = 0; kvs < 2; ++kvs) {
      // ---- S^T[kv][q] = K_tile . Q^T : A = K (row=kv), B = Q (col=q)
      f32x16 st = {};
      __builtin_amdgcn_s_setprio(1);
#pragma unroll
      for (int ds = 0; ds < 4; ++ds) {
        const int row = kvs * 32 + lo;
        bf16x8 kf = ld8(kl + row * 128 +
                        ((ds * 32 + hi5 * 16) ^ ((row & 7) << 4)));
        st = __builtin_amdgcn_mfma_f32_32x32x16_bf16(kf, qf[ds], st, 0, 0, 0);
      }
      __builtin_amdgcn_s_setprio(0);
      // ---- row max for q = lo: in-lane tree + cross-half
      float pm = fmaxf(st[0], st[1]);
      pm = fmaxf(pm, fmaxf(st[2],  st[3]));
      pm = fmaxf(pm, fmaxf(st[4],  st[5]));
      pm = fmaxf(pm, fmaxf(st[6],  st[7]));
      pm = fmaxf(pm, fmaxf(st[8],  st[9]));
      pm = fmaxf(pm, fmaxf(st[10], st[11]));
      pm = fmaxf(pm, fmaxf(st[12], st[13]));
      pm = fmaxf(pm, fmaxf(st[14], st[15]));
      pm = fmaxf(pm, __shfl_xor(pm, 32));
      // ---- defer-max: rescale only when max grew > 8 (exp2 domain)
      if (!__all(pm - mrun <= 8.f)) {
        const float mn = fmaxf(mrun, pm);
        const float f = __builtin_amdgcn_exp2f(mrun - mn);
        mrun = mn;
        lrun *= f;
#pragma unroll
        for (int r = 0; r < 16; ++r) {
          const int crow = (r & 3) + 8 * (r >> 2) + 4 * hi5;
          const float fr = __shfl(f, crow);   // f lives at lane==q
          acc[0][r] *= fr;
          acc[1][r] *= fr;
        }
      }
      // ---- P = exp2(S - m), per-lane partial l
      float p[16];
#pragma unroll
      for (int r = 0; r < 16; ++r) {
        p[r] = __builtin_amdgcn_exp2f(st[r] - mrun);
        lrun += p[r];
      }
      // ---- pack P to PV A-frags: 8 cvt_pk + 4 permlane32_swap per subtile
#pragma unroll
      for (int ksl = 0; ksl < 2; ++ksl) {
        u32 A0 = cvtpk(p[8 * ksl + 0], p[8 * ksl + 1]);
        u32 A1 = cvtpk(p[8 * ksl + 2], p[8 * ksl + 3]);
        u32 B0 = cvtpk(p[8 * ksl + 4], p[8 * ksl + 5]);
        u32 B1 = cvtpk(p[8 * ksl + 6], p[8 * ksl + 7]);
        // swap: vdst.hi <-> vsrc.lo  =>  A0 = {own lo-quad | partner lo-quad}
        asm("v_permlane32_swap_b32 %0, %1" : "+v"(A0), "+v"(B0));
        asm("v_permlane32_swap_b32 %0, %1" : "+v"(A1), "+v"(B1));
        u32x4 pw; pw.x = A0; pw.y = A1; pw.z = B0; pw.w = B1;
        const bf16x8 pa = __builtin_bit_cast(bf16x8, pw);
        const int ks = kvs * 2 + ksl;          // kv-slice of 16 within tile
        __builtin_amdgcn_s_setprio(1);
#pragma unroll
        for (int ds2 = 0; ds2 < 2; ++ds2) {
          const int row = ds2 * 32 + lo;
          bf16x8 vf = ld8(vl + row * 128 +
                          ((ks * 32 + hi5 * 16) ^ ((row & 7) << 4)));
          acc[ds2] = __builtin_amdgcn_mfma_f32_32x32x16_bf16(pa, vf, acc[ds2],
                                                             0, 0, 0);
        }
        __builtin_amdgcn_s_setprio(0);
      }
    }
    __syncthreads();   // drains vmcnt(0): next tile landed; LDS reads done
  }
  // ---- finalize: l = own + partner half; normalize; write [S,B,E] bf16
  lrun += __shfl_xor(lrun, 32);
  const float inv = 1.0f / lrun;                // at q = lo
  const int b = bh >> 3, h = bh & 7;
#pragma unroll
  for (int r = 0; r < 16; ++r) {
    const int crow = (r & 3) + 8 * (r >> 2) + 4 * hi5;
    const float ir = __shfl(inv, crow);
    const int s = q0 + crow;
#pragma unroll
    for (int ds2 = 0; ds2 < 2; ++ds2) {
      const int col = h * 64 + ds2 * 32 + lo;
      attn[(size_t)(s * 2 + b) * 512 + col] = f2bf(acc[ds2][r] * ir);
    }
  }
#undef STAGE
}

// ---------------- launcher ------------------------------------------------
extern "C" void kernel_launch(void* const* d_in, const int* in_sizes, int n_in,
                              void* d_out, int out_size, void* d_ws, size_t ws_size,
                              hipStream_t stream) {
  const float* x     = (const float*)d_in[0];
  const float* w_in  = (const float*)d_in[1];
  const float* b_in  = (const float*)d_in[2];
  const float* w_out = (const float*)d_in[3];
  const float* b_out = (const float*)d_in[4];
  float* out = (float*)d_out;
  char* ws = (char*)d_ws;
  // layout (bytes):
  u16* xb  = (u16*)(ws);               // 8,388,608   x bf16 [8192][512]
  u16* wb  = (u16*)(ws + 8388608);     // 1,572,864   in_proj_w bf16 [1536][512]
  u16* ob  = (u16*)(ws + 9961472);     //   524,288   out_w bf16 [512][512]
  u16* qb  = (u16*)(ws + 10485760);    // 8,388,608   q bf16 [16][4096][64] (pre-scaled)
  u16* kb  = (u16*)(ws + 18874368);    // 8,388,608   k
  u16* vb  = (u16*)(ws + 27262976);    // 8,388,608   v
  u16* vtb = (u16*)(ws + 35651584);    // 8,388,608   v^T [16][64][4096]
  u16* attn = xb;                      // alias: xb fully consumed by gemm<0>

  cvt_kernel<<<5120, 256, 0, stream>>>(x, w_in, w_out, xb, wb, ob);
  gemm_bt<0><<<dim3(64, 12), 256, 0, stream>>>(xb, wb, b_in, qb, kb, vb,
                                               nullptr, 8192, 1536, 512);
  transpose_v<<<dim3(64, 16), 256, 0, stream>>>(vb, vtb);
  fa_kernel<<<1024, 128, 0, stream>>>(qb, kb, vtb, attn);
  gemm_bt<1><<<dim3(64, 4), 256, 0, stream>>>(attn, ob, b_out, nullptr, nullptr,
                                              nullptr, out, 8192, 512, 512);
}

// Round 5
// 154.954 us; speedup vs baseline: 2.1689x; 1.1163x over previous
//
#include <hip/hip_runtime.h>

typedef unsigned short u16;
typedef unsigned int   u32;
typedef short bf16x8 __attribute__((ext_vector_type(8)));
typedef float f32x4  __attribute__((ext_vector_type(4)));
typedef float f32x16 __attribute__((ext_vector_type(16)));
typedef u32   u32x4  __attribute__((ext_vector_type(4)));

#define QK_SCALE 0.18033688011112042f   // 0.125 * log2(e): fold softmax exp2 into q

__device__ __forceinline__ u16 f2bf(float f) {
  u32 u = __builtin_bit_cast(u32, f);
  u = (u + 0x7FFFu + ((u >> 16) & 1u)) >> 16;   // RNE
  return (u16)u;
}

__device__ __forceinline__ u32 cvtpk(float lo, float hi) {
  u32 r;
  asm("v_cvt_pk_bf16_f32 %0, %1, %2" : "=v"(r) : "v"(lo), "v"(hi));
  return r;
}

__device__ __forceinline__ void gload16(void* lds, const void* g) {
  __builtin_amdgcn_global_load_lds(
      (const __attribute__((address_space(1))) u32*)g,
      (__attribute__((address_space(3))) u32*)lds, 16, 0, 0);
}

__device__ __forceinline__ bf16x8 ld8(const void* p) {
  return *(const bf16x8*)p;
}

// ---------------- kernel 1: fp32 -> bf16 convert (x, in_proj_w, out_w) ----
__global__ __launch_bounds__(256) void cvt_kernel(
    const float* __restrict__ x, const float* __restrict__ w1,
    const float* __restrict__ w2,
    u16* __restrict__ xb, u16* __restrict__ wb, u16* __restrict__ ob) {
  int i = blockIdx.x * 256 + threadIdx.x;      // one float4 per thread
  const float* src; u16* dst; int off;
  if (i < 1048576)            { src = x;  dst = xb; off = i; }
  else if (i < 1048576+196608){ src = w1; dst = wb; off = i - 1048576; }
  else                        { src = w2; dst = ob; off = i - 1245184; }
  float4 v = ((const float4*)src)[off];
  ushort4 o;
  o.x = f2bf(v.x); o.y = f2bf(v.y); o.z = f2bf(v.z); o.w = f2bf(v.w);
  ((ushort4*)dst)[off] = o;
}

// ---------------- kernel 2/5: bf16 GEMM  C = A * B^T  (+bias) -------------
template<int MODE>
__global__ __launch_bounds__(256, 2) void gemm_bt(
    const u16* __restrict__ A, const u16* __restrict__ Bm,
    const float* __restrict__ bias,
    u16* __restrict__ q_out, u16* __restrict__ k_out, u16* __restrict__ v_out,
    float* __restrict__ f_out, int M, int N, int K) {
  __shared__ __attribute__((aligned(16))) u16 As[128 * 64];
  __shared__ __attribute__((aligned(16))) u16 Bs[128 * 64];
  const int tid = threadIdx.x, lane = tid & 63, w = tid >> 6;
  const int wm = w >> 1, wn = w & 1;
  const int lo = lane & 15, hi = lane >> 4;
  const int m0 = blockIdx.x * 128, n0 = blockIdx.y * 128;
  f32x4 acc[4][4] = {};
  const int srow = lane >> 3;                   // row within 8-row chunk
  const int skc  = (lane & 7) ^ srow;           // pre-swizzled source chunk
  const int nk = K >> 6;
  for (int kt = 0; kt < nk; ++kt) {
    __syncthreads();                            // WAR on LDS
    const int k0 = kt * 64;
#pragma unroll
    for (int c = 0; c < 4; ++c) {
      const int ch = w * 4 + c;                 // 0..15, wave-uniform
      const int row = ch * 8 + srow;
      gload16((char*)As + ch * 1024, A  + (size_t)(m0 + row) * K + k0 + skc * 8);
      gload16((char*)Bs + ch * 1024, Bm + (size_t)(n0 + row) * K + k0 + skc * 8);
    }
    __syncthreads();                            // vmcnt(0) drained by compiler
#pragma unroll
    for (int kk = 0; kk < 2; ++kk) {
      bf16x8 af[4], bfr[4];
#pragma unroll
      for (int mi = 0; mi < 4; ++mi) {
        const int row = wm * 64 + mi * 16 + lo;
        const int kc = kk * 4 + hi;
        af[mi] = ld8((const char*)As + row * 128 + ((kc ^ (row & 7)) << 4));
      }
#pragma unroll
      for (int ni = 0; ni < 4; ++ni) {
        const int row = wn * 64 + ni * 16 + lo;
        const int kc = kk * 4 + hi;
        bfr[ni] = ld8((const char*)Bs + row * 128 + ((kc ^ (row & 7)) << 4));
      }
#pragma unroll
      for (int mi = 0; mi < 4; ++mi)
#pragma unroll
        for (int ni = 0; ni < 4; ++ni)
          acc[mi][ni] = __builtin_amdgcn_mfma_f32_16x16x32_bf16(
              af[mi], bfr[ni], acc[mi][ni], 0, 0, 0);
    }
  }
  // epilogue
#pragma unroll
  for (int mi = 0; mi < 4; ++mi)
#pragma unroll
    for (int ni = 0; ni < 4; ++ni) {
      const int gn = n0 + wn * 64 + ni * 16 + lo;
      const float bv = bias[gn];
#pragma unroll
      for (int r = 0; r < 4; ++r) {
        const int gm = m0 + wm * 64 + mi * 16 + hi * 4 + r;
        float val = acc[mi][ni][r] + bv;
        if (MODE == 0) {
          const int s = gm >> 1, b = gm & 1;
          const int sec = gn >> 9, e = gn & 511;
          const int h = e >> 6, d = e & 63;
          const size_t o = (((size_t)(b * 8 + h) * 4096 + s) << 6) + d;
          if (sec == 0)      q_out[o] = f2bf(val * QK_SCALE);
          else if (sec == 1) k_out[o] = f2bf(val);
          else               v_out[o] = f2bf(val);
        } else {
          f_out[(size_t)gm * N + gn] = val;
        }
      }
    }
}

// ---------------- kernel 3: V [BH][S][64] -> V^T [BH][64][S] --------------
__global__ __launch_bounds__(256) void transpose_v(
    const u16* __restrict__ v, u16* __restrict__ vt) {
  __shared__ __attribute__((aligned(16))) u16 T[64 * 72];
  const int bh = blockIdx.y, s0 = blockIdx.x * 64;
  const int t = threadIdx.x;
#pragma unroll
  for (int i = 0; i < 2; ++i) {
    const int idx = t + i * 256;                // 0..511
    const int row = idx >> 3, c = idx & 7;
    uint4 d = *(const uint4*)(v + ((size_t)bh * 4096 + s0 + row) * 64 + c * 8);
    *(uint4*)(&T[row * 72 + c * 8]) = d;
  }
  __syncthreads();
#pragma unroll
  for (int i = 0; i < 2; ++i) {
    const int idx = t + i * 256;
    const int dcol = idx >> 3, sc = idx & 7;
    u16 tmp[8];
#pragma unroll
    for (int j = 0; j < 8; ++j) tmp[j] = T[(sc * 8 + j) * 72 + dcol];
    *(uint4*)(vt + ((size_t)bh * 64 + dcol) * 4096 + s0 + sc * 8) = *(const uint4*)tmp;
  }
}

// ---------------- kernel 4: flash attention (swapped-QK, in-reg softmax) --
// 4 waves/block, 32 q-rows/wave (block = 128 rows) -> grid 512.
// Staged K/V tiles shared by 4 waves (halves L2 traffic + staging issue).
// QK for both 32-kv subtiles computed as one 8-MFMA cluster; softmax/pack/PV
// per-subtile is byte-exact R2 (known good): per-subtile defer check,
// __shfl_xor cross-half, pack via cvt_pk + permlane32_swap.
__global__ __launch_bounds__(256, 2) void fa_kernel(
    const u16* __restrict__ q, const u16* __restrict__ k,
    const u16* __restrict__ vt, u16* __restrict__ attn) {
  // [2 bufs][ K tile 64x64 bf16 (8KB) | V^T tile 64x64 bf16 (8KB) ]
  __shared__ __attribute__((aligned(16))) char S_lds[2][16384];
  const int tid = threadIdx.x, lane = tid & 63, w = tid >> 6;   // w = 0..3
  const int lo = lane & 31, hi5 = lane >> 5;
  // XCD-aware mapping: 2 heads per XCD so K/V (2 MB) fit that XCD's L2
  const int wg = blockIdx.x;                    // 0..511
  const int xcd = wg & 7, idx = wg >> 3;        // idx 0..63
  const int bh = xcd * 2 + (idx >> 5), qb = idx & 31;
  const int q0 = qb * 128 + w * 32;
  const size_t hb = (size_t)bh * 4096 * 64;
  const u16* kbase = k + hb;
  const u16* vbase = vt + hb;                   // [64 d][4096 s] per head
  // Q as B-operand frags: lane holds Q[q0+lo][ds*16 + hi5*8 + j]
  bf16x8 qf[4];
#pragma unroll
  for (int ds = 0; ds < 4; ++ds)
    qf[ds] = ld8(q + hb + (size_t)(q0 + lo) * 64 + ds * 16 + hi5 * 8);

  f32x16 acc[2] = {};                 // O[q=crow(r,hi5)][dv=ds2*32+lo]
  float mrun = -1e30f, lrun = 0.f;    // softmax state for q = lo (dup per half)

  const int srow8 = lane >> 3;        // row within 8-row chunk
  const int skc   = (lane & 7) ^ srow8;  // pre-swizzled source 16B-slot

  // stage K[kv0..+64][64] and V^T[0..64 d][kv0..+64] into buf (linear LDS,
  // source pre-swizzled so reads use byte ^ ((row&7)<<4)); 4 waves split work
#define STAGE(buf, kv0)                                                       \
  {                                                                           \
    char* sb = S_lds[buf];                                                    \
    _Pragma("unroll")                                                         \
    for (int i = 0; i < 2; ++i) {                                             \
      const int c = w + i * 4;            /* chunks 0..7, wave-uniform */     \
      const int row = c * 8 + srow8;                                          \
      gload16(sb + c * 1024,                                                  \
              kbase + (size_t)((kv0) + row) * 64 + skc * 8);                  \
      gload16(sb + 8192 + c * 1024,                                           \
              vbase + (size_t)row * 4096 + (kv0) + skc * 8);                  \
    }                                                                         \
  }

  STAGE(0, 0);
  __syncthreads();

  for (int kb = 0; kb < 64; ++kb) {
    const int cur = kb & 1;
    if (kb < 63) STAGE(cur ^ 1, (kb + 1) * 64);
    const char* kl = S_lds[cur];
    const char* vl = S_lds[cur] + 8192;
    // ---- QK cluster: S^T[kv][q] for both 32-kv subtiles (8 MFMA)
    f32x16 stt[2] = {};
    __builtin_amdgcn_s_setprio(1);
#pragma unroll
    for (int ds = 0; ds < 4; ++ds) {
      const int r0 = lo, r1 = 32 + lo;
      const int col = ds * 32 + hi5 * 16;
      bf16x8 kf0 = ld8(kl + r0 * 128 + (col ^ ((r0 & 7) << 4)));
      bf16x8 kf1 = ld8(kl + r1 * 128 + (col ^ ((r1 & 7) << 4)));
      stt[0] = __builtin_amdgcn_mfma_f32_32x32x16_bf16(kf0, qf[ds], stt[0], 0,0,0);
      stt[1] = __builtin_amdgcn_mfma_f32_32x32x16_bf16(kf1, qf[ds], stt[1], 0,0,0);
    }
    __builtin_amdgcn_s_setprio(0);
    // ---- per-subtile softmax/pack/PV (byte-exact R2 known-good path)
#pragma unroll
    for (int kvs = 0; kvs < 2; ++kvs) {
      const f32x16 st = stt[kvs];
      // row max for q = lo: in-lane chain + cross-half
      float pm = fmaxf(st[0], st[1]);
      pm = fmaxf(pm, fmaxf(st[2],  st[3]));
      pm = fmaxf(pm, fmaxf(st[4],  st[5]));
      pm = fmaxf(pm, fmaxf(st[6],  st[7]));
      pm = fmaxf(pm, fmaxf(st[8],  st[9]));
      pm = fmaxf(pm, fmaxf(st[10], st[11]));
      pm = fmaxf(pm, fmaxf(st[12], st[13]));
      pm = fmaxf(pm, fmaxf(st[14], st[15]));
      pm = fmaxf(pm, __shfl_xor(pm, 32));
      // defer-max: rescale only when max grew > 8 (exp2 domain)
      if (!__all(pm - mrun <= 8.f)) {
        const float mn = fmaxf(mrun, pm);
        const float f = __builtin_amdgcn_exp2f(mrun - mn);
        mrun = mn;
        lrun *= f;
#pragma unroll
        for (int r = 0; r < 16; ++r) {
          const int crow = (r & 3) + 8 * (r >> 2) + 4 * hi5;
          const float fr = __shfl(f, crow);   // f lives at lane==q
          acc[0][r] *= fr;
          acc[1][r] *= fr;
        }
      }
      // P = exp2(S - m), per-lane partial l
      float p[16];
#pragma unroll
      for (int r = 0; r < 16; ++r) {
        p[r] = __builtin_amdgcn_exp2f(st[r] - mrun);
        lrun += p[r];
      }
      // pack P to PV A-frags: 8 cvt_pk + 4 permlane32_swap per subtile
#pragma unroll
      for (int ksl = 0; ksl < 2; ++ksl) {
        u32 A0 = cvtpk(p[8 * ksl + 0], p[8 * ksl + 1]);
        u32 A1 = cvtpk(p[8 * ksl + 2], p[8 * ksl + 3]);
        u32 B0 = cvtpk(p[8 * ksl + 4], p[8 * ksl + 5]);
        u32 B1 = cvtpk(p[8 * ksl + 6], p[8 * ksl + 7]);
        // swap: vdst.hi <-> vsrc.lo  =>  A0 = {own lo-quad | partner lo-quad}
        asm("v_permlane32_swap_b32 %0, %1" : "+v"(A0), "+v"(B0));
        asm("v_permlane32_swap_b32 %0, %1" : "+v"(A1), "+v"(B1));
        u32x4 pw; pw.x = A0; pw.y = A1; pw.z = B0; pw.w = B1;
        const bf16x8 pa = __builtin_bit_cast(bf16x8, pw);
        const int ks = kvs * 2 + ksl;          // kv-slice of 16 within tile
        __builtin_amdgcn_s_setprio(1);
#pragma unroll
        for (int ds2 = 0; ds2 < 2; ++ds2) {
          const int row = ds2 * 32 + lo;
          bf16x8 vf = ld8(vl + row * 128 +
                          ((ks * 32 + hi5 * 16) ^ ((row & 7) << 4)));
          acc[ds2] = __builtin_amdgcn_mfma_f32_32x32x16_bf16(pa, vf, acc[ds2],
                                                             0, 0, 0);
        }
        __builtin_amdgcn_s_setprio(0);
      }
    }
    __syncthreads();   // drains vmcnt(0): next tile landed; LDS reads done
  }
  // ---- finalize: l = own + partner half; normalize; write [S,B,E] bf16
  lrun += __shfl_xor(lrun, 32);
  const float inv = 1.0f / lrun;                // at q = lo
  const int b = bh >> 3, h = bh & 7;
#pragma unroll
  for (int r = 0; r < 16; ++r) {
    const int crow = (r & 3) + 8 * (r >> 2) + 4 * hi5;
    const float ir = __shfl(inv, crow);
    const int s = q0 + crow;
#pragma unroll
    for (int ds2 = 0; ds2 < 2; ++ds2) {
      const int col = h * 64 + ds2 * 32 + lo;
      attn[(size_t)(s * 2 + b) * 512 + col] = f2bf(acc[ds2][r] * ir);
    }
  }
#undef STAGE
}

// ---------------- launcher ------------------------------------------------
extern "C" void kernel_launch(void* const* d_in, const int* in_sizes, int n_in,
                              void* d_out, int out_size, void* d_ws, size_t ws_size,
                              hipStream_t stream) {
  const float* x     = (const float*)d_in[0];
  const float* w_in  = (const float*)d_in[1];
  const float* b_in  = (const float*)d_in[2];
  const float* w_out = (const float*)d_in[3];
  const float* b_out = (const float*)d_in[4];
  float* out = (float*)d_out;
  char* ws = (char*)d_ws;
  // layout (bytes):
  u16* xb  = (u16*)(ws);               // 8,388,608   x bf16 [8192][512]
  u16* wb  = (u16*)(ws + 8388608);     // 1,572,864   in_proj_w bf16 [1536][512]
  u16* ob  = (u16*)(ws + 9961472);     //   524,288   out_w bf16 [512][512]
  u16* qb  = (u16*)(ws + 10485760);    // 8,388,608   q bf16 [16][4096][64] (pre-scaled)
  u16* kb  = (u16*)(ws + 18874368);    // 8,388,608   k
  u16* vb  = (u16*)(ws + 27262976);    // 8,388,608   v
  u16* vtb = (u16*)(ws + 35651584);    // 8,388,608   v^T [16][64][4096]
  u16* attn = xb;                      // alias: xb fully consumed by gemm<0>

  cvt_kernel<<<5120, 256, 0, stream>>>(x, w_in, w_out, xb, wb, ob);
  gemm_bt<0><<<dim3(64, 12), 256, 0, stream>>>(xb, wb, b_in, qb, kb, vb,
                                               nullptr, 8192, 1536, 512);
  transpose_v<<<dim3(64, 16), 256, 0, stream>>>(vb, vtb);
  fa_kernel<<<512, 256, 0, stream>>>(qb, kb, vtb, attn);
  gemm_bt<1><<<dim3(64, 4), 256, 0, stream>>>(attn, ob, b_out, nullptr, nullptr,
                                              nullptr, out, 8192, 512, 512);
}